// Round 9
// baseline (327.813 us; speedup 1.0000x reference)
//
#include <hip/hip_runtime.h>

typedef unsigned short u16;
typedef short v8s __attribute__((ext_vector_type(8)));
typedef short v4s16 __attribute__((ext_vector_type(4)));
typedef float v4f __attribute__((ext_vector_type(4)));

#if defined(__has_builtin)
#  if __has_builtin(__builtin_amdgcn_exp2f)
#    define EXP2F(x) __builtin_amdgcn_exp2f(x)
#  else
#    define EXP2F(x) exp2f(x)
#  endif
#else
#  define EXP2F(x) exp2f(x)
#endif

__device__ __forceinline__ float bf2f(u16 u){
  union { float f; unsigned int i; } c; c.i = ((unsigned int)u) << 16; return c.f;
}
__device__ __forceinline__ u16 f2bf(float f){
  union { float f; unsigned int i; } c; c.f = f;
  unsigned int r = c.i + 0x7FFFu + ((c.i >> 16) & 1u);
  return (u16)(r >> 16);
}
__device__ __forceinline__ unsigned int cvt_pk_bf16(float lo, float hi){
  unsigned int r;
  asm("v_cvt_pk_bf16_f32 %0, %1, %2" : "=v"(r) : "v"(lo), "v"(hi));
  return r;
}

// ---------------- fp32 -> bf16 conversion of all inputs + ctx zero --------------
struct CvtArgs {
  const float* s[13];
  u16* d[13];
  int n[13];
  int bstart[14];
  float* ctxz;
};
__global__ __launch_bounds__(256) void cvt_all(CvtArgs a) {
  if ((int)blockIdx.x >= a.bstart[13]) {      // last block: zero ctx (2048 floats)
    float4 z = {0.f, 0.f, 0.f, 0.f};
    ((float4*)a.ctxz)[threadIdx.x] = z;
    ((float4*)a.ctxz)[256 + threadIdx.x] = z;
    return;
  }
  int j = 0;
  #pragma unroll
  for (int i = 1; i < 13; i++) if ((int)blockIdx.x >= a.bstart[i]) j = i;
  const int lb = blockIdx.x - a.bstart[j];
  const long base = (long)lb * 1024 + threadIdx.x * 4;
  if (base < a.n[j]) {
    const float4 f = *(const float4*)&a.s[j][base];
    v4s16 o;
    o.x = (short)f2bf(f.x); o.y = (short)f2bf(f.y);
    o.z = (short)f2bf(f.z); o.w = (short)f2bf(f.w);
    *(v4s16*)&a.d[j][base] = o;
  }
}

// ---------------- w_comb = w_in1 @ w_out0, b_comb = w_in1 @ b_out0 + b_in1 ------
// Per head h (16 blocks): collapses layer0-out-proj into layer1-in-proj (exact:
// no nonlinearity between them). w_comb[h] is 192x64, inner dim o=64.
__global__ __launch_bounds__(256) void wcomb_k(
    const u16* __restrict__ hinw, const u16* __restrict__ hinb,
    const u16* __restrict__ houtw, const u16* __restrict__ houtb,
    u16* __restrict__ wcomb, u16* __restrict__ bcomb)
{
  const int h = blockIdx.x, tid = threadIdx.x;
  const u16* win1  = hinw  + ((size_t)h*2 + 1) * 192*64;   // (192,64)
  const u16* bin1  = hinb  + ((size_t)h*2 + 1) * 192;
  const u16* wout0 = houtw + (size_t)h*2 * 64*64;          // (64,64)
  const u16* bout0 = houtb + (size_t)h*2 * 64;
  __shared__ float wo[64][64];
  __shared__ float bo[64];
  for (int i = tid; i < 4096; i += 256) wo[i >> 6][i & 63] = bf2f(wout0[i]);
  if (tid < 64) bo[tid] = bf2f(bout0[tid]);
  __syncthreads();
  // outputs: 192*64 = 12288, 48 per thread
  for (int idx = tid; idx < 12288; idx += 256) {
    const int n = idx >> 6, i = idx & 63;
    const u16* wr = win1 + n*64;
    float s = 0.f;
    #pragma unroll 8
    for (int o = 0; o < 64; o++) s += bf2f(wr[o]) * wo[o][i];
    wcomb[((size_t)h*192 + n)*64 + i] = f2bf(s);
  }
  if (tid < 192) {
    const u16* wr = win1 + tid*64;
    float s = bf2f(bin1[tid]);
    #pragma unroll 8
    for (int o = 0; o < 64; o++) s += bf2f(wr[o]) * bo[o];
    bcomb[(size_t)h*192 + tid] = f2bf(s);
  }
}

// ---------------- batched GEMM: C[g][M,N] = A[g][M,K] @ W[g][N,K]^T + bias[g] ----
// Double-buffered LDS: 1 barrier per K-iter. Issue-early/write-late staging.
// Epilogues: EPI=0 bf16 C, EPI=1 fp32 C, EPI=2 fused RoPE+split, EPI=3 ctx mean.
template<int BM, int BN, int EPI>
__global__ __launch_bounds__(256) void gemm_nt(
    const u16* __restrict__ A, long aBatch, int lda,
    const u16* __restrict__ W, long wBatch,
    const u16* __restrict__ bias, long bBatch,
    void* __restrict__ Cp, long cBatch, int ldc,
    int K,
    const u16* __restrict__ cosb, const u16* __restrict__ sinb,
    u16* __restrict__ q_r, u16* __restrict__ k_r, u16* __restrict__ v_out,
    float* __restrict__ ctxp)
{
  constexpr int BK = 64, LDT = BK + 8;
  constexpr int AC = BM / 32;
  constexpr int BC = BN / 32;
  A    += (long)blockIdx.z * aBatch;
  W    += (long)blockIdx.z * wBatch;
  bias += (long)blockIdx.z * bBatch;
  const int row0 = blockIdx.y * BM, col0 = blockIdx.x * BN;
  __shared__ __align__(16) u16 As[2][BM * LDT];
  __shared__ __align__(16) u16 Bs[2][BN * LDT];
  const int tid = threadIdx.x, wid = tid >> 6, lane = tid & 63;
  constexpr int FM = (BM/2)/16, FN = (BN/2)/16;
  const int wr = (wid >> 1) * (BM/2), wc = (wid & 1) * (BN/2);
  v4f acc[FM][FN] = {};
  const int lr = lane & 15, lk = (lane >> 4) * 8;

  v8s areg[AC], breg[BC];
  auto loadAB = [&](int k0) {
    #pragma unroll
    for (int i = 0; i < AC; i++) {
      const int c = tid + i*256, r = c >> 3, cc = (c & 7) * 8;
      areg[i] = *(const v8s*)&A[(long)(row0 + r)*lda + k0 + cc];
    }
    #pragma unroll
    for (int i = 0; i < BC; i++) {
      const int c = tid + i*256, r = c >> 3, cc = (c & 7) * 8;
      breg[i] = *(const v8s*)&W[(long)(col0 + r)*K + k0 + cc];
    }
  };
  auto writeAB = [&](int buf) {
    #pragma unroll
    for (int i = 0; i < AC; i++) {
      const int c = tid + i*256, r = c >> 3, cc = (c & 7) * 8;
      *(v8s*)&As[buf][r*LDT + cc] = areg[i];
    }
    #pragma unroll
    for (int i = 0; i < BC; i++) {
      const int c = tid + i*256, r = c >> 3, cc = (c & 7) * 8;
      *(v8s*)&Bs[buf][r*LDT + cc] = breg[i];
    }
  };

  loadAB(0); writeAB(0);
  __syncthreads();
  const int NIT = K / BK;
  for (int it = 0; it < NIT; it++) {
    const int cur = it & 1;
    if (it + 1 < NIT) loadAB((it + 1) * BK);   // issue next tile early
    #pragma unroll
    for (int ks = 0; ks < BK; ks += 32) {
      v8s af[FM], bfv[FN];
      #pragma unroll
      for (int i = 0; i < FM; i++) af[i]  = *(const v8s*)&As[cur][(wr + i*16 + lr)*LDT + ks + lk];
      #pragma unroll
      for (int j = 0; j < FN; j++) bfv[j] = *(const v8s*)&Bs[cur][(wc + j*16 + lr)*LDT + ks + lk];
      #pragma unroll
      for (int i = 0; i < FM; i++)
        #pragma unroll
        for (int j = 0; j < FN; j++)
          acc[i][j] = __builtin_amdgcn_mfma_f32_16x16x32_bf16(af[i], bfv[j], acc[i][j], 0, 0, 0);
    }
    if (it + 1 < NIT) writeAB(cur ^ 1);        // write-late into other buffer
    __syncthreads();
  }
  const int lc = lane & 15, lq = (lane >> 4) * 4;
  if (EPI <= 1) {
    u16*   Cb = (u16*)Cp   + (long)blockIdx.z * cBatch;
    float* Cf = (float*)Cp + (long)blockIdx.z * cBatch;
    #pragma unroll
    for (int i = 0; i < FM; i++)
      #pragma unroll
      for (int j = 0; j < FN; j++) {
        const int cidx = col0 + wc + j*16 + lc;
        const float bv = bf2f(bias[cidx]);
        #pragma unroll
        for (int q = 0; q < 4; q++) {
          const int r = row0 + wr + i*16 + lq + q;
          if (EPI == 1) Cf[(long)r*ldc + cidx] = acc[i][j][q] + bv;
          else          Cb[(long)r*ldc + cidx] = f2bf(acc[i][j][q] + bv);
        }
      }
  } else if (EPI == 2) {
    // rope + split: cidx -> (which, head, d); rows -> (b, t)
    #pragma unroll
    for (int i = 0; i < FM; i++)
      #pragma unroll
      for (int j = 0; j < FN; j++) {
        const int cidx = col0 + wc + j*16 + lc;
        const float bv = bf2f(bias[cidx]);
        const int which = cidx >> 10;            // uniform per (i,j)
        const int h = (cidx & 1023) >> 6;
        const int d = cidx & 63;
        u16* dst = (which == 0) ? q_r : (which == 1) ? k_r : v_out;
        #pragma unroll
        for (int q = 0; q < 4; q++) {
          const int r = row0 + wr + i*16 + lq + q;
          const int b = r >> 10, t = r & 1023;
          float val = acc[i][j][q] + bv;
          float par = __shfl_xor(val, 1);        // partner d (d^1)
          float outv;
          if (which == 2) {
            outv = val;
          } else {
            const int i2 = d >> 1;
            const float cc = bf2f(cosb[(t << 5) + i2]);
            const float ss = bf2f(sinb[(t << 5) + i2]);
            outv = (d & 1) ? __builtin_fmaf(par, ss,  val*cc)
                           : __builtin_fmaf(val, cc, -par*ss);
          }
          dst[((long)((b << 4) + h)*1024 + t)*64 + d] = f2bf(outv);
        }
      }
  } else {  // EPI == 3: column-mean accumulation into ctx
    const float inv = 1.0f/1024.0f;
    const int hb = (blockIdx.z << 1) + (row0 >> 10);
    #pragma unroll
    for (int j = 0; j < FN; j++) {
      const int cidx = col0 + wc + j*16 + lc;
      const float bv = bf2f(bias[cidx]);
      float p = (float)(FM*4) * bv;
      #pragma unroll
      for (int i = 0; i < FM; i++)
        #pragma unroll
        for (int q = 0; q < 4; q++) p += acc[i][j][q];
      p += __shfl_xor(p, 16);
      p += __shfl_xor(p, 32);
      if (lane < 16) atomicAdd(&ctxp[hb*64 + cidx], p * inv);
    }
  }
}

// ---------------- MFMA flash attention v4 (KBLK=128, swapped layout) -------------
template<int D>
__global__ __launch_bounds__(512) void flash_mfma(
    const u16* __restrict__ qb, const u16* __restrict__ kb,
    const u16* __restrict__ vb, u16* __restrict__ ob,
    float scale, int n1, int n2,
    long q0, long q1, long q2, int qs,
    long k0, long k1, long k2, int ks,
    long v0, long v1, long v2, int vs,
    long o0, long o1, long o2, int os)
{
  constexpr int KBLK = 128;
  constexpr int NF  = KBLK / 16;
  constexpr int NKB = KBLK / 32;
  constexpr int KD2 = (D < 32) ? 32 : D;
  constexpr int LDK = KD2 + 8;
  constexpr int LDV = KBLK + 8;
  constexpr int KD  = KD2 / 32;
  constexpr int NSUB = D / 16;
  constexpr int KCH = KBLK * (KD2/8);
  constexpr int VCH = (D/8) * KBLK;
  constexpr int KIT = (KCH + 511) / 512;
  constexpr int VIT = (VCH + 511) / 512;
  __shared__ __align__(16) u16 Ks[2][KBLK * LDK];
  __shared__ __align__(16) u16 Vs[2][D * LDV];

  const int tid = threadIdx.x, wid = tid >> 6, lane = tid & 63;
  const int lr = lane & 15, lg = lane >> 4;
  const int prob = blockIdx.x;
  const int p2 = prob % n2, p1 = (prob / n2) % n1, p0 = prob / (n2 * n1);
  const u16* qp = qb + p0*q0 + p1*q1 + p2*q2;
  const u16* kp = kb + p0*k0 + p1*k1 + p2*k2;
  const u16* vp = vb + p0*v0 + p1*v1 + p2*v2;
  u16* op = ob + p0*o0 + p1*o1 + p2*o2;

  const int ta = blockIdx.y;
  const int tbt = 15 - ta;
  const int wtile = (wid & 4) ? tbt : ta;
  const int wq = wtile * 64 + (wid & 3) * 16;
  const int nchb = (tbt >> 1) + 1;
  const float scale2 = scale * 1.44269504f;

  v8s qf[KD];
  #pragma unroll
  for (int kd = 0; kd < KD; kd++) {
    const int dof = kd*32 + lg*8;
    v8s val = {};
    if (dof < D) val = *(const v8s*)&qp[(long)(wq + lr)*qs + dof];
    qf[kd] = val;
  }

  v4f Of[NSUB] = {};
  float m2 = -1.0e30f, l = 0.f;

  v8s kreg[KIT], vreg[VIT];
  auto loadK = [&](int kc) {
    #pragma unroll
    for (int i = 0; i < KIT; i++) {
      const int idx = tid + i*512;
      if (idx < KCH) {
        const int key = idx / (KD2/8), d8 = (idx % (KD2/8)) * 8;
        v8s t = {};
        if (d8 < D) t = *(const v8s*)&kp[(long)(kc + key)*ks + d8];
        kreg[i] = t;
      }
    }
  };
  auto loadV = [&](int kc) {
    #pragma unroll
    for (int i = 0; i < VIT; i++) {
      const int idx = tid + i*512;
      if (idx < VCH) {
        const int key = idx / (D/8), d8 = (idx % (D/8)) * 8;
        vreg[i] = *(const v8s*)&vp[(long)(kc + key)*vs + d8];
      }
    }
  };
  auto writeKV = [&](int buf) {
    #pragma unroll
    for (int i = 0; i < KIT; i++) {
      const int idx = tid + i*512;
      if (idx < KCH) {
        const int key = idx / (KD2/8), d8 = (idx % (KD2/8)) * 8;
        *(v8s*)&Ks[buf][key*LDK + d8] = kreg[i];
      }
    }
    #pragma unroll
    for (int i = 0; i < VIT; i++) {
      const int idx = tid + i*512;
      if (idx < VCH) {
        const int key = idx / (D/8), d8 = (idx % (D/8)) * 8;
        #pragma unroll
        for (int j = 0; j < 8; j++) Vs[buf][(d8+j)*LDV + key] = vreg[i][j];
      }
    }
  };

  loadK(0); loadV(0); writeKV(0);
  __syncthreads();

  for (int c = 0; c < nchb; c++) {
    const int cur = c & 1, nxt = cur ^ 1;
    if (c + 1 < nchb) { loadK((c+1)*KBLK); loadV((c+1)*KBLK); }
    const int kc = c * KBLK;
    if (kc <= wq + 15) {
      v4f sf[NF];
      #pragma unroll
      for (int f = 0; f < NF; f++) {
        v4f s = {};
        #pragma unroll
        for (int kd = 0; kd < KD; kd++) {
          const v8s kf = *(const v8s*)&Ks[cur][(f*16 + lr)*LDK + kd*32 + lg*8];
          s = __builtin_amdgcn_mfma_f32_16x16x32_bf16(kf, qf[kd], s, 0, 0, 0);
        }
        sf[f] = s;
      }
      const int qg = wq + lr;
      if (kc + KBLK - 1 > wq) {
        #pragma unroll
        for (int f = 0; f < NF; f++)
          #pragma unroll
          for (int r = 0; r < 4; r++)
            sf[f][r] = (kc + 16*f + 4*lg + r <= qg) ? sf[f][r] : -3.0e38f;
      }
      float mx = -3.0e38f;
      #pragma unroll
      for (int f = 0; f < NF; f++)
        mx = fmaxf(mx, fmaxf(fmaxf(sf[f][0], sf[f][1]), fmaxf(sf[f][2], sf[f][3])));
      mx = fmaxf(mx, __shfl_xor(mx, 16));
      mx = fmaxf(mx, __shfl_xor(mx, 32));
      const float mn2 = fmaxf(m2, mx * scale2);
      const float al = EXP2F(m2 - mn2);
      m2 = mn2;
      float pv[NF][4];
      float ps = 0.f;
      #pragma unroll
      for (int f = 0; f < NF; f++) {
        #pragma unroll
        for (int r = 0; r < 4; r++)
          pv[f][r] = EXP2F(__builtin_fmaf(sf[f][r], scale2, -mn2));
        ps += (pv[f][0] + pv[f][1]) + (pv[f][2] + pv[f][3]);
      }
      ps += __shfl_xor(ps, 16);
      ps += __shfl_xor(ps, 32);
      l = l * al + ps;
      #pragma unroll
      for (int sub = 0; sub < NSUB; sub++)
        #pragma unroll
        for (int r = 0; r < 4; r++) Of[sub][r] *= al;
      unsigned int pw[2*NF];
      #pragma unroll
      for (int f = 0; f < NF; f++) {
        pw[2*f]   = cvt_pk_bf16(pv[f][0], pv[f][1]);
        pw[2*f+1] = cvt_pk_bf16(pv[f][2], pv[f][3]);
      }
      #pragma unroll
      for (int kb2 = 0; kb2 < NKB; kb2++) {
        union { unsigned int w[4]; v8s v; } pb;
        pb.w[0] = pw[4*kb2];   pb.w[1] = pw[4*kb2+1];
        pb.w[2] = pw[4*kb2+2]; pb.w[3] = pw[4*kb2+3];
        #pragma unroll
        for (int sub = 0; sub < NSUB; sub++) {
          union { v4s16 h[2]; v8s v; } va;
          const int vbase = (sub*16 + lr)*LDV + kb2*32 + 4*lg;
          va.h[0] = *(const v4s16*)&Vs[cur][vbase];
          va.h[1] = *(const v4s16*)&Vs[cur][vbase + 16];
          Of[sub] = __builtin_amdgcn_mfma_f32_16x16x32_bf16(va.v, pb.v, Of[sub], 0, 0, 0);
        }
      }
    }
    if (c + 1 < nchb) writeKV(nxt);
    __syncthreads();
  }
  const float rl = __builtin_amdgcn_rcpf(l);
  #pragma unroll
  for (int sub = 0; sub < NSUB; sub++) {
    unsigned int w0 = cvt_pk_bf16(Of[sub][0]*rl, Of[sub][1]*rl);
    unsigned int w1 = cvt_pk_bf16(Of[sub][2]*rl, Of[sub][3]*rl);
    unsigned int* dst = (unsigned int*)&op[(long)(wq + lr)*os + sub*16 + 4*lg];
    dst[0] = w0; dst[1] = w1;
  }
}

// ---------------- fused A,B projections + rank-8 V update (per (h,b) block) -----
__global__ __launch_bounds__(256) void abdelta_k(const float* __restrict__ ctx,
    const u16* __restrict__ toA, const u16* __restrict__ toB,
    u16* __restrict__ v)
{
  const int hb = blockIdx.x;               // h*2 + b
  const int h = hb >> 1, b = hb & 1;
  const int tid = threadIdx.x;
  __shared__ float Am[512];                // n = d*8+r
  __shared__ float Bm[512];                // n = r*64+d
  __shared__ float cf[64];
  if (tid < 64) cf[tid] = ctx[hb*64 + tid];
  __syncthreads();
  for (int n = tid; n < 512; n += 256) {
    const u16* wa = toA + ((long)h*512 + n) * 64;
    const u16* wb = toB + ((long)h*512 + n) * 64;
    float sa = 0.f, sb = 0.f;
    #pragma unroll 8
    for (int i = 0; i < 64; i++) { sa += cf[i]*bf2f(wa[i]); sb += cf[i]*bf2f(wb[i]); }
    Am[n] = sa; Bm[n] = sb;
  }
  __syncthreads();
  u16* base = v + ((long)(b*16 + h)*1024)*64;
  for (int t = tid; t < 1024; t += 256) {
    u16* row = base + (long)t*64;
    float tmp[8] = {};
    #pragma unroll 8
    for (int d = 0; d < 64; d++) {
      const float vd = bf2f(row[d]);
      #pragma unroll
      for (int r = 0; r < 8; r++) tmp[r] += vd * Am[d*8 + r];
    }
    #pragma unroll 8
    for (int d = 0; d < 64; d++) {
      float s = 0.f;
      #pragma unroll
      for (int r = 0; r < 8; r++) s += tmp[r] * Bm[r*64 + d];
      row[d] = f2bf(bf2f(row[d]) + 2.0f * s);   // SCALE = 16/8 = 2
    }
  }
}

extern "C" void kernel_launch(void* const* d_in, const int* in_sizes, int n_in,
                              void* d_out, int out_size, void* d_ws, size_t ws_size,
                              hipStream_t stream) {
  (void)in_sizes; (void)n_in; (void)out_size; (void)ws_size;
  float* out = (float*)d_out;

  char* ws = (char*)d_ws;
  size_t off = 0;
  auto alloc = [&](size_t bytes){ void* p = ws + off; off += (bytes + 255) & ~(size_t)255; return p; };

  static const int ns[13] = {2097152, 32768, 32768, 3145728, 3072, 1048576, 1024,
                             393216, 6144, 131072, 2048, 524288, 524288};
  u16* bufs[13];
  for (int i = 0; i < 13; i++) bufs[i] = (u16*)alloc((size_t)ns[i] * 2);
  u16* xb    = bufs[0];
  u16* cosb  = bufs[1];
  u16* sinb  = bufs[2];
  u16* attnw = bufs[3];
  u16* attnb = bufs[4];
  u16* projw = bufs[5];
  u16* projb = bufs[6];
  u16* hinw  = bufs[7];
  u16* hinb  = bufs[8];
  u16* houtw = bufs[9];
  u16* houtb = bufs[10];
  u16* toAb  = bufs[11];
  u16* toBb  = bufs[12];

  u16* q_r   = (u16*)alloc(2097152ull*2);  // (B,H,T,64)
  u16* k_r   = (u16*)alloc(2097152ull*2);
  u16* v     = (u16*)alloc(2097152ull*2);
  u16* tqkv  = (u16*)alloc(6291456ull*2);  // (H, B*T, 192)
  u16* tatt  = (u16*)alloc(2097152ull*2);  // (H, B*T, 64)
  u16* yat   = (u16*)alloc(2097152ull*2);  // (B,T,C)
  u16* wcomb = (u16*)alloc(196608ull*2);   // (H,192,64)
  u16* bcomb = (u16*)alloc(3072ull*2);     // (H,192)
  float* ctx  = (float*)alloc(2048*4);

  // 0. convert all inputs fp32 -> bf16 (+ zero ctx in the extra block)
  CvtArgs ca;
  int bacc = 0;
  for (int i = 0; i < 13; i++) {
    ca.s[i] = (const float*)d_in[i];
    ca.d[i] = bufs[i];
    ca.n[i] = ns[i];
    ca.bstart[i] = bacc;
    bacc += (ns[i] + 1023) / 1024;
  }
  ca.bstart[13] = bacc;
  ca.ctxz = ctx;
  cvt_all<<<dim3(bacc + 1), 256, 0, stream>>>(ca);

  // 0b. collapse layer0-out-proj into layer1-in-proj
  wcomb_k<<<dim3(16), 256, 0, stream>>>(hinw, hinb, houtw, houtb, wcomb, bcomb);

  // 1. qkv = x @ c_attn_w^T + b, fused RoPE + (B,H,T,64) split
  gemm_nt<64,64,2><<<dim3(48,32,1),256,0,stream>>>(xb,0,1024, attnw,0, attnb,0,
      nullptr,0,0, 1024, cosb, sinb, q_r, k_r, v, nullptr);

  // 2. tiny hyper-net
  gemm_nt<64,64,0><<<dim3(3,32,16),256,0,stream>>>(xb, 64L, 1024,
      hinw, (long)2*192*64, hinb, (long)2*192,
      tqkv, (long)2048*192, 192, 64,
      nullptr, nullptr, nullptr, nullptr, nullptr, nullptr);
  flash_mfma<16><<<dim3(128,8),512,0,stream>>>(tqkv, tqkv+64, tqkv+128, tatt,
      0.25f, 2, 4,
      (long)2048*192, (long)1024*192, 16L, 192,
      (long)2048*192, (long)1024*192, 16L, 192,
      (long)2048*192, (long)1024*192, 16L, 192,
      (long)2048*64,  (long)1024*64,  16L, 64);
  // att0 @ w_comb^T + b_comb  ->  layer-1 qkv  (out-proj0 folded in)
  gemm_nt<64,64,0><<<dim3(3,32,16),256,0,stream>>>(tatt, (long)2048*64, 64,
      wcomb, (long)192*64, bcomb, 192L,
      tqkv, (long)2048*192, 192, 64,
      nullptr, nullptr, nullptr, nullptr, nullptr, nullptr);
  flash_mfma<16><<<dim3(128,8),512,0,stream>>>(tqkv, tqkv+64, tqkv+128, tatt,
      0.25f, 2, 4,
      (long)2048*192, (long)1024*192, 16L, 192,
      (long)2048*192, (long)1024*192, 16L, 192,
      (long)2048*192, (long)1024*192, 16L, 192,
      (long)2048*64,  (long)1024*64,  16L, 64);
  gemm_nt<64,64,3><<<dim3(1,32,16),256,0,stream>>>(tatt, (long)2048*64, 64,
      houtw + (size_t)64*64, (long)2*64*64, houtb + 64, (long)2*64,
      nullptr, 0, 0, 64,
      nullptr, nullptr, nullptr, nullptr, nullptr, ctx);

  // 3. fused A/B projections + rank-8 V update
  abdelta_k<<<dim3(32),256,0,stream>>>(ctx, toAb, toBb, v);

  // 4. main causal attention (32 problems, D=64)
  flash_mfma<64><<<dim3(32,8),512,0,stream>>>(q_r, k_r, v, yat,
      0.125f, 16, 1,
      (long)16*1024*64, (long)1024*64, 0L, 64,
      (long)16*1024*64, (long)1024*64, 0L, 64,
      (long)16*1024*64, (long)1024*64, 0L, 64,
      (long)1024*1024,  64L,           0L, 1024);

  // 5. out = yat @ c_proj_w^T + b (fp32 out)
  gemm_nt<64,64,1><<<dim3(16,32,1),256,0,stream>>>(yat,0,1024, projw,0, projb,0,
      out,0,1024, 1024,
      nullptr, nullptr, nullptr, nullptr, nullptr, nullptr);
}

// Round 10
// 273.048 us; speedup vs baseline: 1.2006x; 1.2006x over previous
//
#include <hip/hip_runtime.h>

typedef unsigned short u16;
typedef short v8s __attribute__((ext_vector_type(8)));
typedef short v4s16 __attribute__((ext_vector_type(4)));
typedef float v4f __attribute__((ext_vector_type(4)));

#if defined(__has_builtin)
#  if __has_builtin(__builtin_amdgcn_exp2f)
#    define EXP2F(x) __builtin_amdgcn_exp2f(x)
#  else
#    define EXP2F(x) exp2f(x)
#  endif
#else
#  define EXP2F(x) exp2f(x)
#endif

__device__ __forceinline__ float bf2f(u16 u){
  union { float f; unsigned int i; } c; c.i = ((unsigned int)u) << 16; return c.f;
}
__device__ __forceinline__ u16 f2bf(float f){
  union { float f; unsigned int i; } c; c.f = f;
  unsigned int r = c.i + 0x7FFFu + ((c.i >> 16) & 1u);
  return (u16)(r >> 16);
}
__device__ __forceinline__ unsigned int cvt_pk_bf16(float lo, float hi){
  unsigned int r;
  asm("v_cvt_pk_bf16_f32 %0, %1, %2" : "=v"(r) : "v"(lo), "v"(hi));
  return r;
}

// ---------------- fp32 -> bf16 conversion of all inputs + ctx zero --------------
struct CvtArgs {
  const float* s[13];
  u16* d[13];
  int n[13];
  int bstart[14];
  float* ctxz;
};
__global__ __launch_bounds__(256) void cvt_all(CvtArgs a) {
  if ((int)blockIdx.x >= a.bstart[13]) {      // last block: zero ctx (2048 floats)
    float4 z = {0.f, 0.f, 0.f, 0.f};
    ((float4*)a.ctxz)[threadIdx.x] = z;
    ((float4*)a.ctxz)[256 + threadIdx.x] = z;
    return;
  }
  int j = 0;
  #pragma unroll
  for (int i = 1; i < 13; i++) if ((int)blockIdx.x >= a.bstart[i]) j = i;
  const int lb = blockIdx.x - a.bstart[j];
  const long base = (long)lb * 1024 + threadIdx.x * 4;
  if (base < a.n[j]) {
    const float4 f = *(const float4*)&a.s[j][base];
    v4s16 o;
    o.x = (short)f2bf(f.x); o.y = (short)f2bf(f.y);
    o.z = (short)f2bf(f.z); o.w = (short)f2bf(f.w);
    *(v4s16*)&a.d[j][base] = o;
  }
}

// ---------------- w_comb = w_in1 @ w_out0, b_comb = w_in1 @ b_out0 + b_in1 ------
// Collapses layer0-out-proj into layer1-in-proj (exact: no nonlinearity).
// Grid (16 heads, 12 n-blocks) x 256 threads; wout0 staged fp32 in LDS;
// each thread: one win1 row (8 x v8s) -> 4 outputs via float4 LDS reads.
__global__ __launch_bounds__(256) void wcomb_k(
    const u16* __restrict__ hinw, const u16* __restrict__ hinb,
    const u16* __restrict__ houtw, const u16* __restrict__ houtb,
    u16* __restrict__ wcomb, u16* __restrict__ bcomb)
{
  const int h = blockIdx.x, nb = blockIdx.y, tid = threadIdx.x;
  const u16* win1  = hinw  + ((size_t)h*2 + 1) * 192*64;   // (192,64)
  const u16* bin1  = hinb  + ((size_t)h*2 + 1) * 192;
  const u16* wout0 = houtw + (size_t)h*2 * 64*64;          // (64,64) o-major
  const u16* bout0 = houtb + (size_t)h*2 * 64;
  __shared__ __align__(16) float wo[64][64];
  __shared__ float bo[64];
  #pragma unroll
  for (int rep = 0; rep < 2; rep++) {
    const int idx = tid*8 + rep*2048;
    const v8s w = *(const v8s*)&wout0[idx];
    const int row = idx >> 6, c0 = idx & 63;
    #pragma unroll
    for (int j = 0; j < 8; j++) wo[row][c0 + j] = bf2f((u16)w[j]);
  }
  if (tid < 64) bo[tid] = bf2f(bout0[tid]);
  __syncthreads();
  const int n  = nb*16 + (tid >> 4);
  const int i0 = (tid & 15) * 4;
  const u16* wr = win1 + n*64;
  float a0 = 0.f, a1 = 0.f, a2 = 0.f, a3 = 0.f;
  #pragma unroll
  for (int o8 = 0; o8 < 8; o8++) {
    const v8s wv = *(const v8s*)&wr[o8*8];
    #pragma unroll
    for (int e = 0; e < 8; e++) {
      const float wf = bf2f((u16)wv[e]);
      const float4 c = *(const float4*)&wo[o8*8 + e][i0];
      a0 = __builtin_fmaf(wf, c.x, a0);
      a1 = __builtin_fmaf(wf, c.y, a1);
      a2 = __builtin_fmaf(wf, c.z, a2);
      a3 = __builtin_fmaf(wf, c.w, a3);
    }
  }
  v4s16 ov;
  ov.x = (short)f2bf(a0); ov.y = (short)f2bf(a1);
  ov.z = (short)f2bf(a2); ov.w = (short)f2bf(a3);
  *(v4s16*)&wcomb[((size_t)h*192 + n)*64 + i0] = ov;
  if (tid < 16) {
    const int nn = nb*16 + tid;
    const u16* wrow = win1 + nn*64;
    float s = bf2f(bin1[nn]);
    #pragma unroll 8
    for (int o = 0; o < 64; o++) s = __builtin_fmaf(bf2f(wrow[o]), bo[o], s);
    bcomb[(size_t)h*192 + nn] = f2bf(s);
  }
}

// ---------------- batched GEMM: C[g][M,N] = A[g][M,K] @ W[g][N,K]^T + bias[g] ----
// Double-buffered LDS: 1 barrier per K-iter. Issue-early/write-late staging.
// Epilogues: EPI=0 bf16 C, EPI=1 fp32 C, EPI=2 fused RoPE+split, EPI=3 ctx mean.
template<int BM, int BN, int EPI>
__global__ __launch_bounds__(256) void gemm_nt(
    const u16* __restrict__ A, long aBatch, int lda,
    const u16* __restrict__ W, long wBatch,
    const u16* __restrict__ bias, long bBatch,
    void* __restrict__ Cp, long cBatch, int ldc,
    int K,
    const u16* __restrict__ cosb, const u16* __restrict__ sinb,
    u16* __restrict__ q_r, u16* __restrict__ k_r, u16* __restrict__ v_out,
    float* __restrict__ ctxp)
{
  constexpr int BK = 64, LDT = BK + 8;
  constexpr int AC = BM / 32;
  constexpr int BC = BN / 32;
  A    += (long)blockIdx.z * aBatch;
  W    += (long)blockIdx.z * wBatch;
  bias += (long)blockIdx.z * bBatch;
  const int row0 = blockIdx.y * BM, col0 = blockIdx.x * BN;
  __shared__ __align__(16) u16 As[2][BM * LDT];
  __shared__ __align__(16) u16 Bs[2][BN * LDT];
  const int tid = threadIdx.x, wid = tid >> 6, lane = tid & 63;
  constexpr int FM = (BM/2)/16, FN = (BN/2)/16;
  const int wr = (wid >> 1) * (BM/2), wc = (wid & 1) * (BN/2);
  v4f acc[FM][FN] = {};
  const int lr = lane & 15, lk = (lane >> 4) * 8;

  v8s areg[AC], breg[BC];
  auto loadAB = [&](int k0) {
    #pragma unroll
    for (int i = 0; i < AC; i++) {
      const int c = tid + i*256, r = c >> 3, cc = (c & 7) * 8;
      areg[i] = *(const v8s*)&A[(long)(row0 + r)*lda + k0 + cc];
    }
    #pragma unroll
    for (int i = 0; i < BC; i++) {
      const int c = tid + i*256, r = c >> 3, cc = (c & 7) * 8;
      breg[i] = *(const v8s*)&W[(long)(col0 + r)*K + k0 + cc];
    }
  };
  auto writeAB = [&](int buf) {
    #pragma unroll
    for (int i = 0; i < AC; i++) {
      const int c = tid + i*256, r = c >> 3, cc = (c & 7) * 8;
      *(v8s*)&As[buf][r*LDT + cc] = areg[i];
    }
    #pragma unroll
    for (int i = 0; i < BC; i++) {
      const int c = tid + i*256, r = c >> 3, cc = (c & 7) * 8;
      *(v8s*)&Bs[buf][r*LDT + cc] = breg[i];
    }
  };

  loadAB(0); writeAB(0);
  __syncthreads();
  const int NIT = K / BK;
  for (int it = 0; it < NIT; it++) {
    const int cur = it & 1;
    if (it + 1 < NIT) loadAB((it + 1) * BK);   // issue next tile early
    #pragma unroll
    for (int ks = 0; ks < BK; ks += 32) {
      v8s af[FM], bfv[FN];
      #pragma unroll
      for (int i = 0; i < FM; i++) af[i]  = *(const v8s*)&As[cur][(wr + i*16 + lr)*LDT + ks + lk];
      #pragma unroll
      for (int j = 0; j < FN; j++) bfv[j] = *(const v8s*)&Bs[cur][(wc + j*16 + lr)*LDT + ks + lk];
      #pragma unroll
      for (int i = 0; i < FM; i++)
        #pragma unroll
        for (int j = 0; j < FN; j++)
          acc[i][j] = __builtin_amdgcn_mfma_f32_16x16x32_bf16(af[i], bfv[j], acc[i][j], 0, 0, 0);
    }
    if (it + 1 < NIT) writeAB(cur ^ 1);        // write-late into other buffer
    __syncthreads();
  }
  const int lc = lane & 15, lq = (lane >> 4) * 4;
  if (EPI <= 1) {
    u16*   Cb = (u16*)Cp   + (long)blockIdx.z * cBatch;
    float* Cf = (float*)Cp + (long)blockIdx.z * cBatch;
    #pragma unroll
    for (int i = 0; i < FM; i++)
      #pragma unroll
      for (int j = 0; j < FN; j++) {
        const int cidx = col0 + wc + j*16 + lc;
        const float bv = bf2f(bias[cidx]);
        #pragma unroll
        for (int q = 0; q < 4; q++) {
          const int r = row0 + wr + i*16 + lq + q;
          if (EPI == 1) Cf[(long)r*ldc + cidx] = acc[i][j][q] + bv;
          else          Cb[(long)r*ldc + cidx] = f2bf(acc[i][j][q] + bv);
        }
      }
  } else if (EPI == 2) {
    // rope + split: cidx -> (which, head, d); rows -> (b, t)
    #pragma unroll
    for (int i = 0; i < FM; i++)
      #pragma unroll
      for (int j = 0; j < FN; j++) {
        const int cidx = col0 + wc + j*16 + lc;
        const float bv = bf2f(bias[cidx]);
        const int which = cidx >> 10;            // uniform per (i,j)
        const int h = (cidx & 1023) >> 6;
        const int d = cidx & 63;
        u16* dst = (which == 0) ? q_r : (which == 1) ? k_r : v_out;
        #pragma unroll
        for (int q = 0; q < 4; q++) {
          const int r = row0 + wr + i*16 + lq + q;
          const int b = r >> 10, t = r & 1023;
          float val = acc[i][j][q] + bv;
          float par = __shfl_xor(val, 1);        // partner d (d^1)
          float outv;
          if (which == 2) {
            outv = val;
          } else {
            const int i2 = d >> 1;
            const float cc = bf2f(cosb[(t << 5) + i2]);
            const float ss = bf2f(sinb[(t << 5) + i2]);
            outv = (d & 1) ? __builtin_fmaf(par, ss,  val*cc)
                           : __builtin_fmaf(val, cc, -par*ss);
          }
          dst[((long)((b << 4) + h)*1024 + t)*64 + d] = f2bf(outv);
        }
      }
  } else {  // EPI == 3: column-mean accumulation into ctx
    const float inv = 1.0f/1024.0f;
    const int hb = (blockIdx.z << 1) + (row0 >> 10);
    #pragma unroll
    for (int j = 0; j < FN; j++) {
      const int cidx = col0 + wc + j*16 + lc;
      const float bv = bf2f(bias[cidx]);
      float p = (float)(FM*4) * bv;
      #pragma unroll
      for (int i = 0; i < FM; i++)
        #pragma unroll
        for (int q = 0; q < 4; q++) p += acc[i][j][q];
      p += __shfl_xor(p, 16);
      p += __shfl_xor(p, 32);
      if (lane < 16) atomicAdd(&ctxp[hb*64 + cidx], p * inv);
    }
  }
}

// ---------------- MFMA flash attention v4 (KBLK=128, swapped layout) -------------
template<int D>
__global__ __launch_bounds__(512) void flash_mfma(
    const u16* __restrict__ qb, const u16* __restrict__ kb,
    const u16* __restrict__ vb, u16* __restrict__ ob,
    float scale, int n1, int n2,
    long q0, long q1, long q2, int qs,
    long k0, long k1, long k2, int ks,
    long v0, long v1, long v2, int vs,
    long o0, long o1, long o2, int os)
{
  constexpr int KBLK = 128;
  constexpr int NF  = KBLK / 16;
  constexpr int NKB = KBLK / 32;
  constexpr int KD2 = (D < 32) ? 32 : D;
  constexpr int LDK = KD2 + 8;
  constexpr int LDV = KBLK + 8;
  constexpr int KD  = KD2 / 32;
  constexpr int NSUB = D / 16;
  constexpr int KCH = KBLK * (KD2/8);
  constexpr int VCH = (D/8) * KBLK;
  constexpr int KIT = (KCH + 511) / 512;
  constexpr int VIT = (VCH + 511) / 512;
  __shared__ __align__(16) u16 Ks[2][KBLK * LDK];
  __shared__ __align__(16) u16 Vs[2][D * LDV];

  const int tid = threadIdx.x, wid = tid >> 6, lane = tid & 63;
  const int lr = lane & 15, lg = lane >> 4;
  const int prob = blockIdx.x;
  const int p2 = prob % n2, p1 = (prob / n2) % n1, p0 = prob / (n2 * n1);
  const u16* qp = qb + p0*q0 + p1*q1 + p2*q2;
  const u16* kp = kb + p0*k0 + p1*k1 + p2*k2;
  const u16* vp = vb + p0*v0 + p1*v1 + p2*v2;
  u16* op = ob + p0*o0 + p1*o1 + p2*o2;

  const int ta = blockIdx.y;
  const int tbt = 15 - ta;
  const int wtile = (wid & 4) ? tbt : ta;
  const int wq = wtile * 64 + (wid & 3) * 16;
  const int nchb = (tbt >> 1) + 1;
  const float scale2 = scale * 1.44269504f;

  v8s qf[KD];
  #pragma unroll
  for (int kd = 0; kd < KD; kd++) {
    const int dof = kd*32 + lg*8;
    v8s val = {};
    if (dof < D) val = *(const v8s*)&qp[(long)(wq + lr)*qs + dof];
    qf[kd] = val;
  }

  v4f Of[NSUB] = {};
  float m2 = -1.0e30f, l = 0.f;

  v8s kreg[KIT], vreg[VIT];
  auto loadK = [&](int kc) {
    #pragma unroll
    for (int i = 0; i < KIT; i++) {
      const int idx = tid + i*512;
      if (idx < KCH) {
        const int key = idx / (KD2/8), d8 = (idx % (KD2/8)) * 8;
        v8s t = {};
        if (d8 < D) t = *(const v8s*)&kp[(long)(kc + key)*ks + d8];
        kreg[i] = t;
      }
    }
  };
  auto loadV = [&](int kc) {
    #pragma unroll
    for (int i = 0; i < VIT; i++) {
      const int idx = tid + i*512;
      if (idx < VCH) {
        const int key = idx / (D/8), d8 = (idx % (D/8)) * 8;
        vreg[i] = *(const v8s*)&vp[(long)(kc + key)*vs + d8];
      }
    }
  };
  auto writeKV = [&](int buf) {
    #pragma unroll
    for (int i = 0; i < KIT; i++) {
      const int idx = tid + i*512;
      if (idx < KCH) {
        const int key = idx / (KD2/8), d8 = (idx % (KD2/8)) * 8;
        *(v8s*)&Ks[buf][key*LDK + d8] = kreg[i];
      }
    }
    #pragma unroll
    for (int i = 0; i < VIT; i++) {
      const int idx = tid + i*512;
      if (idx < VCH) {
        const int key = idx / (D/8), d8 = (idx % (D/8)) * 8;
        #pragma unroll
        for (int j = 0; j < 8; j++) Vs[buf][(d8+j)*LDV + key] = vreg[i][j];
      }
    }
  };

  loadK(0); loadV(0); writeKV(0);
  __syncthreads();

  for (int c = 0; c < nchb; c++) {
    const int cur = c & 1, nxt = cur ^ 1;
    if (c + 1 < nchb) { loadK((c+1)*KBLK); loadV((c+1)*KBLK); }
    const int kc = c * KBLK;
    if (kc <= wq + 15) {
      v4f sf[NF];
      #pragma unroll
      for (int f = 0; f < NF; f++) {
        v4f s = {};
        #pragma unroll
        for (int kd = 0; kd < KD; kd++) {
          const v8s kf = *(const v8s*)&Ks[cur][(f*16 + lr)*LDK + kd*32 + lg*8];
          s = __builtin_amdgcn_mfma_f32_16x16x32_bf16(kf, qf[kd], s, 0, 0, 0);
        }
        sf[f] = s;
      }
      const int qg = wq + lr;
      if (kc + KBLK - 1 > wq) {
        #pragma unroll
        for (int f = 0; f < NF; f++)
          #pragma unroll
          for (int r = 0; r < 4; r++)
            sf[f][r] = (kc + 16*f + 4*lg + r <= qg) ? sf[f][r] : -3.0e38f;
      }
      float mx = -3.0e38f;
      #pragma unroll
      for (int f = 0; f < NF; f++)
        mx = fmaxf(mx, fmaxf(fmaxf(sf[f][0], sf[f][1]), fmaxf(sf[f][2], sf[f][3])));
      mx = fmaxf(mx, __shfl_xor(mx, 16));
      mx = fmaxf(mx, __shfl_xor(mx, 32));
      const float mn2 = fmaxf(m2, mx * scale2);
      const float al = EXP2F(m2 - mn2);
      m2 = mn2;
      float pv[NF][4];
      float ps = 0.f;
      #pragma unroll
      for (int f = 0; f < NF; f++) {
        #pragma unroll
        for (int r = 0; r < 4; r++)
          pv[f][r] = EXP2F(__builtin_fmaf(sf[f][r], scale2, -mn2));
        ps += (pv[f][0] + pv[f][1]) + (pv[f][2] + pv[f][3]);
      }
      ps += __shfl_xor(ps, 16);
      ps += __shfl_xor(ps, 32);
      l = l * al + ps;
      #pragma unroll
      for (int sub = 0; sub < NSUB; sub++)
        #pragma unroll
        for (int r = 0; r < 4; r++) Of[sub][r] *= al;
      unsigned int pw[2*NF];
      #pragma unroll
      for (int f = 0; f < NF; f++) {
        pw[2*f]   = cvt_pk_bf16(pv[f][0], pv[f][1]);
        pw[2*f+1] = cvt_pk_bf16(pv[f][2], pv[f][3]);
      }
      #pragma unroll
      for (int kb2 = 0; kb2 < NKB; kb2++) {
        union { unsigned int w[4]; v8s v; } pb;
        pb.w[0] = pw[4*kb2];   pb.w[1] = pw[4*kb2+1];
        pb.w[2] = pw[4*kb2+2]; pb.w[3] = pw[4*kb2+3];
        #pragma unroll
        for (int sub = 0; sub < NSUB; sub++) {
          union { v4s16 h[2]; v8s v; } va;
          const int vbase = (sub*16 + lr)*LDV + kb2*32 + 4*lg;
          va.h[0] = *(const v4s16*)&Vs[cur][vbase];
          va.h[1] = *(const v4s16*)&Vs[cur][vbase + 16];
          Of[sub] = __builtin_amdgcn_mfma_f32_16x16x32_bf16(va.v, pb.v, Of[sub], 0, 0, 0);
        }
      }
    }
    if (c + 1 < nchb) writeKV(nxt);
    __syncthreads();
  }
  const float rl = __builtin_amdgcn_rcpf(l);
  #pragma unroll
  for (int sub = 0; sub < NSUB; sub++) {
    unsigned int w0 = cvt_pk_bf16(Of[sub][0]*rl, Of[sub][1]*rl);
    unsigned int w1 = cvt_pk_bf16(Of[sub][2]*rl, Of[sub][3]*rl);
    unsigned int* dst = (unsigned int*)&op[(long)(wq + lr)*os + sub*16 + 4*lg];
    dst[0] = w0; dst[1] = w1;
  }
}

// ---------------- fused A,B projections + rank-8 V update (per (h,b) block) -----
__global__ __launch_bounds__(256) void abdelta_k(const float* __restrict__ ctx,
    const u16* __restrict__ toA, const u16* __restrict__ toB,
    u16* __restrict__ v)
{
  const int hb = blockIdx.x;               // h*2 + b
  const int h = hb >> 1, b = hb & 1;
  const int tid = threadIdx.x;
  __shared__ float Am[512];                // n = d*8+r
  __shared__ float Bm[512];                // n = r*64+d
  __shared__ float cf[64];
  if (tid < 64) cf[tid] = ctx[hb*64 + tid];
  __syncthreads();
  for (int n = tid; n < 512; n += 256) {
    const u16* wa = toA + ((long)h*512 + n) * 64;
    const u16* wb = toB + ((long)h*512 + n) * 64;
    float sa = 0.f, sb = 0.f;
    #pragma unroll 8
    for (int i = 0; i < 64; i++) { sa += cf[i]*bf2f(wa[i]); sb += cf[i]*bf2f(wb[i]); }
    Am[n] = sa; Bm[n] = sb;
  }
  __syncthreads();
  u16* base = v + ((long)(b*16 + h)*1024)*64;
  for (int t = tid; t < 1024; t += 256) {
    u16* row = base + (long)t*64;
    float tmp[8] = {};
    #pragma unroll 8
    for (int d = 0; d < 64; d++) {
      const float vd = bf2f(row[d]);
      #pragma unroll
      for (int r = 0; r < 8; r++) tmp[r] += vd * Am[d*8 + r];
    }
    #pragma unroll 8
    for (int d = 0; d < 64; d++) {
      float s = 0.f;
      #pragma unroll
      for (int r = 0; r < 8; r++) s += tmp[r] * Bm[r*64 + d];
      row[d] = f2bf(bf2f(row[d]) + 2.0f * s);   // SCALE = 16/8 = 2
    }
  }
}

extern "C" void kernel_launch(void* const* d_in, const int* in_sizes, int n_in,
                              void* d_out, int out_size, void* d_ws, size_t ws_size,
                              hipStream_t stream) {
  (void)in_sizes; (void)n_in; (void)out_size; (void)ws_size;
  float* out = (float*)d_out;

  char* ws = (char*)d_ws;
  size_t off = 0;
  auto alloc = [&](size_t bytes){ void* p = ws + off; off += (bytes + 255) & ~(size_t)255; return p; };

  static const int ns[13] = {2097152, 32768, 32768, 3145728, 3072, 1048576, 1024,
                             393216, 6144, 131072, 2048, 524288, 524288};
  u16* bufs[13];
  for (int i = 0; i < 13; i++) bufs[i] = (u16*)alloc((size_t)ns[i] * 2);
  u16* xb    = bufs[0];
  u16* cosb  = bufs[1];
  u16* sinb  = bufs[2];
  u16* attnw = bufs[3];
  u16* attnb = bufs[4];
  u16* projw = bufs[5];
  u16* projb = bufs[6];
  u16* hinw  = bufs[7];
  u16* hinb  = bufs[8];
  u16* houtw = bufs[9];
  u16* houtb = bufs[10];
  u16* toAb  = bufs[11];
  u16* toBb  = bufs[12];

  u16* q_r   = (u16*)alloc(2097152ull*2);  // (B,H,T,64)
  u16* k_r   = (u16*)alloc(2097152ull*2);
  u16* v     = (u16*)alloc(2097152ull*2);
  u16* tqkv  = (u16*)alloc(6291456ull*2);  // (H, B*T, 192)
  u16* tatt  = (u16*)alloc(2097152ull*2);  // (H, B*T, 64)
  u16* yat   = (u16*)alloc(2097152ull*2);  // (B,T,C)
  u16* wcomb = (u16*)alloc(196608ull*2);   // (H,192,64)
  u16* bcomb = (u16*)alloc(3072ull*2);     // (H,192)
  float* ctx  = (float*)alloc(2048*4);

  // 0. convert all inputs fp32 -> bf16 (+ zero ctx in the extra block)
  CvtArgs ca;
  int bacc = 0;
  for (int i = 0; i < 13; i++) {
    ca.s[i] = (const float*)d_in[i];
    ca.d[i] = bufs[i];
    ca.n[i] = ns[i];
    ca.bstart[i] = bacc;
    bacc += (ns[i] + 1023) / 1024;
  }
  ca.bstart[13] = bacc;
  ca.ctxz = ctx;
  cvt_all<<<dim3(bacc + 1), 256, 0, stream>>>(ca);

  // 0b. collapse layer0-out-proj into layer1-in-proj (192 blocks, vectorized)
  wcomb_k<<<dim3(16, 12), 256, 0, stream>>>(hinw, hinb, houtw, houtb, wcomb, bcomb);

  // 1. qkv = x @ c_attn_w^T + b, fused RoPE + (B,H,T,64) split
  gemm_nt<64,64,2><<<dim3(48,32,1),256,0,stream>>>(xb,0,1024, attnw,0, attnb,0,
      nullptr,0,0, 1024, cosb, sinb, q_r, k_r, v, nullptr);

  // 2. tiny hyper-net
  gemm_nt<64,64,0><<<dim3(3,32,16),256,0,stream>>>(xb, 64L, 1024,
      hinw, (long)2*192*64, hinb, (long)2*192,
      tqkv, (long)2048*192, 192, 64,
      nullptr, nullptr, nullptr, nullptr, nullptr, nullptr);
  flash_mfma<16><<<dim3(128,8),512,0,stream>>>(tqkv, tqkv+64, tqkv+128, tatt,
      0.25f, 2, 4,
      (long)2048*192, (long)1024*192, 16L, 192,
      (long)2048*192, (long)1024*192, 16L, 192,
      (long)2048*192, (long)1024*192, 16L, 192,
      (long)2048*64,  (long)1024*64,  16L, 64);
  // att0 @ w_comb^T + b_comb  ->  layer-1 qkv  (out-proj0 folded in)
  gemm_nt<64,64,0><<<dim3(3,32,16),256,0,stream>>>(tatt, (long)2048*64, 64,
      wcomb, (long)192*64, bcomb, 192L,
      tqkv, (long)2048*192, 192, 64,
      nullptr, nullptr, nullptr, nullptr, nullptr, nullptr);
  flash_mfma<16><<<dim3(128,8),512,0,stream>>>(tqkv, tqkv+64, tqkv+128, tatt,
      0.25f, 2, 4,
      (long)2048*192, (long)1024*192, 16L, 192,
      (long)2048*192, (long)1024*192, 16L, 192,
      (long)2048*192, (long)1024*192, 16L, 192,
      (long)2048*64,  (long)1024*64,  16L, 64);
  gemm_nt<64,64,3><<<dim3(1,32,16),256,0,stream>>>(tatt, (long)2048*64, 64,
      houtw + (size_t)64*64, (long)2*64*64, houtb + 64, (long)2*64,
      nullptr, 0, 0, 64,
      nullptr, nullptr, nullptr, nullptr, nullptr, ctx);

  // 3. fused A/B projections + rank-8 V update
  abdelta_k<<<dim3(32),256,0,stream>>>(ctx, toAb, toBb, v);

  // 4. main causal attention (32 problems, D=64)
  flash_mfma<64><<<dim3(32,8),512,0,stream>>>(q_r, k_r, v, yat,
      0.125f, 16, 1,
      (long)16*1024*64, (long)1024*64, 0L, 64,
      (long)16*1024*64, (long)1024*64, 0L, 64,
      (long)16*1024*64, (long)1024*64, 0L, 64,
      (long)1024*1024,  64L,           0L, 1024);

  // 5. out = yat @ c_proj_w^T + b (fp32 out)
  gemm_nt<64,64,1><<<dim3(16,32,1),256,0,stream>>>(yat,0,1024, projw,0, projb,0,
      out,0,1024, 1024,
      nullptr, nullptr, nullptr, nullptr, nullptr, nullptr);
}